// Round 8
// baseline (426.764 us; speedup 1.0000x reference)
//
#include <hip/hip_runtime.h>

#define C      21
#define HW4    65536      // float4 groups per 512x512 plane
#define NGRP   1048576    // 16*512*512/4
#define NBLK   2048
#define TICKET 63         // ws slot for done-counter (hist uses 0..62)

typedef float f4 __attribute__((ext_vector_type(4)));
typedef int   i4 __attribute__((ext_vector_type(4)));

// __launch_bounds__(256, 1): min 1 wave/EU -> VGPR budget 512. Without this the
// backend compiled the fused kernel at VGPR=28 (R4/R7: occupancy-minimization
// heuristic), serializing all loads -> 4.6x slowdown.
__global__ __launch_bounds__(256, 1) void iou_kernel(
    const f4* __restrict__ pred, const i4* __restrict__ tgt,
    unsigned int* __restrict__ hist, float* __restrict__ out) {
  __shared__ unsigned int sh[3 * C];
  __shared__ int sh_last;
  const int tid = threadIdx.x;
  if (tid < 3 * C) sh[tid] = 0;
  __syncthreads();

  const int lane = tid & 63;
  unsigned int cp = 0, ct = 0, ci = 0;   // lane c owns class c's counts

  const int gstart = blockIdx.x * 256 + tid;

#pragma unroll
  for (int q = 0; q < 2; ++q) {                    // NGRP / (NBLK*256) == 2
    const int g    = gstart + q * (NBLK * 256);
    const int b    = g >> 16;
    const int hw4  = g & (HW4 - 1);
    const int base = ((b * C) << 16) + hw4;        // f4 index of channel 0

    // ---- argmax over 21 channels, 4 pixels: unconditional chunks of 5 ----
    f4 best = pred[base];
    int i0 = 0, i1 = 0, i2 = 0, i3 = 0;
#pragma unroll
    for (int cc = 1; cc < C; cc += 5) {            // 1 + 4*5 = 21
      f4 v[5];
#pragma unroll
      for (int j = 0; j < 5; ++j)
        v[j] = pred[base + ((cc + j) << 16)];
#pragma unroll
      for (int j = 0; j < 5; ++j) {
        const int c = cc + j;
        if (v[j][0] > best[0]) { best[0] = v[j][0]; i0 = c; }
        if (v[j][1] > best[1]) { best[1] = v[j][1]; i1 = c; }
        if (v[j][2] > best[2]) { best[2] = v[j][2]; i2 = c; }
        if (v[j][3] > best[3]) { best[3] = v[j][3]; i3 = c; }
      }
    }

    const i4 t = tgt[g];

    // ---- per-wave ballot histogram: lane c accumulates class c ----
    const unsigned long long m0 = __ballot(i0 == t[0]);
    const unsigned long long m1 = __ballot(i1 == t[1]);
    const unsigned long long m2 = __ballot(i2 == t[2]);
    const unsigned long long m3 = __ballot(i3 == t[3]);

#pragma unroll
    for (int c = 0; c < C; ++c) {
      const unsigned long long p0 = __ballot(i0 == c);
      const unsigned long long p1 = __ballot(i1 == c);
      const unsigned long long p2 = __ballot(i2 == c);
      const unsigned long long p3 = __ballot(i3 == c);
      const unsigned int np_ = (unsigned)__popcll(p0) + (unsigned)__popcll(p1)
                             + (unsigned)__popcll(p2) + (unsigned)__popcll(p3);
      const unsigned int ni_ = (unsigned)__popcll(p0 & m0) + (unsigned)__popcll(p1 & m1)
                             + (unsigned)__popcll(p2 & m2) + (unsigned)__popcll(p3 & m3);
      const unsigned int nt_ = (unsigned)__popcll(__ballot(t[0] == c))
                             + (unsigned)__popcll(__ballot(t[1] == c))
                             + (unsigned)__popcll(__ballot(t[2] == c))
                             + (unsigned)__popcll(__ballot(t[3] == c));
      if (lane == c) { cp += np_; ct += nt_; ci += ni_; }
    }
  }

  // ---- wave -> block (LDS), block -> global ----
  if (lane < C) {
    atomicAdd(&sh[lane], cp);
    atomicAdd(&sh[C + lane], ct);
    atomicAdd(&sh[2 * C + lane], ci);
  }
  __syncthreads();
  if (tid < 3 * C) atomicAdd(&hist[tid], sh[tid]);

  // ---- last-block-done fused finalize (saves the finalize dispatch) ----
  __threadfence();                           // this block's hist atomics visible
  __syncthreads();
  if (tid == 0) {
    const unsigned int o = atomicAdd(&hist[TICKET], 1u);
    sh_last = (o == NBLK - 1);
  }
  __syncthreads();
  if (sh_last && tid < 64) {
    float iou = 0.0f;
    if (tid < C) {
      // read through the L2 coherence point (atomic RMW of 0)
      const float p = (float)atomicAdd(&hist[tid], 0u);
      const float t = (float)atomicAdd(&hist[C + tid], 0u);
      const float i = (float)atomicAdd(&hist[2 * C + tid], 0u);
      const float u = p + t - i;
      iou = (u > 0.0f) ? (i / (u + 1e-6f)) : 0.0f;
    }
#pragma unroll
    for (int off = 32; off > 0; off >>= 1) iou += __shfl_down(iou, off);
    if (tid == 0) out[0] = iou / (float)C;
  }
}

extern "C" void kernel_launch(void* const* d_in, const int* in_sizes, int n_in,
                              void* d_out, int out_size, void* d_ws, size_t ws_size,
                              hipStream_t stream) {
  const f4* pred = (const f4*)d_in[0];
  const i4* tgt  = (const i4*)d_in[1];
  float*    out  = (float*)d_out;
  unsigned int* hist = (unsigned int*)d_ws;

  // zero 63 counters + ticket every call (ws poisoned once, never re-poisoned)
  hipMemsetAsync(d_ws, 0, 64 * sizeof(unsigned int), stream);

  iou_kernel<<<NBLK, 256, 0, stream>>>(pred, tgt, hist, out);
}

// Round 9
// 99.757 us; speedup vs baseline: 4.2780x; 4.2780x over previous
//
#include <hip/hip_runtime.h>

#define NUM_CLASSES 21
#define HW4   65536      // (512*512)/4
#define NGRP  1048576    // 16*512*512/4  (float4 pixel groups)

__global__ __launch_bounds__(256) void iou_hist_kernel(
    const float4* __restrict__ pred, const int4* __restrict__ tgt,
    unsigned int* __restrict__ hist) {
  __shared__ unsigned int sh[3 * NUM_CLASSES];
  const int tid = threadIdx.x;
  if (tid < 3 * NUM_CLASSES) sh[tid] = 0;
  __syncthreads();

  const int lane = tid & 63;
  unsigned int cp = 0, ct = 0, ci = 0;   // lane c owns class c's counts

  const int gstart  = blockIdx.x * blockDim.x + tid;
  const int gstride = gridDim.x * blockDim.x;

  for (int g = gstart; g < NGRP; g += gstride) {
    const int b    = g >> 16;           // batch index (HW/4 = 65536 groups per image)
    const int hw4  = g & (HW4 - 1);
    const int base = b * NUM_CLASSES;

    // argmax over 21 channels, 4 pixels at a time (strict > keeps first max)
    float4 best = pred[(base << 16) + hw4];
    int i0 = 0, i1 = 0, i2 = 0, i3 = 0;
#pragma unroll
    for (int c = 1; c < NUM_CLASSES; ++c) {
      float4 v = pred[((base + c) << 16) + hw4];
      if (v.x > best.x) { best.x = v.x; i0 = c; }
      if (v.y > best.y) { best.y = v.y; i1 = c; }
      if (v.z > best.z) { best.z = v.z; i2 = c; }
      if (v.w > best.w) { best.w = v.w; i3 = c; }
    }

    const int4 t = tgt[g];

    // per-wave ballot histogram: lane c accumulates class c
#pragma unroll
    for (int c = 0; c < NUM_CLASSES; ++c) {
      unsigned int np_ = (unsigned)__popcll(__ballot(i0 == c))
                       + (unsigned)__popcll(__ballot(i1 == c))
                       + (unsigned)__popcll(__ballot(i2 == c))
                       + (unsigned)__popcll(__ballot(i3 == c));
      unsigned int nt_ = (unsigned)__popcll(__ballot(t.x == c))
                       + (unsigned)__popcll(__ballot(t.y == c))
                       + (unsigned)__popcll(__ballot(t.z == c))
                       + (unsigned)__popcll(__ballot(t.w == c));
      unsigned int ni_ = (unsigned)__popcll(__ballot(i0 == c && t.x == c))
                       + (unsigned)__popcll(__ballot(i1 == c && t.y == c))
                       + (unsigned)__popcll(__ballot(i2 == c && t.z == c))
                       + (unsigned)__popcll(__ballot(i3 == c && t.w == c));
      if (lane == c) { cp += np_; ct += nt_; ci += ni_; }
    }
  }

  // wave -> block (LDS), block -> global
  if (lane < NUM_CLASSES) {
    atomicAdd(&sh[lane], cp);
    atomicAdd(&sh[NUM_CLASSES + lane], ct);
    atomicAdd(&sh[2 * NUM_CLASSES + lane], ci);
  }
  __syncthreads();
  if (tid < 3 * NUM_CLASSES) atomicAdd(&hist[tid], sh[tid]);
}

__global__ __launch_bounds__(64) void iou_finalize_kernel(
    const unsigned int* __restrict__ hist, float* __restrict__ out) {
  const int lane = threadIdx.x;
  float iou = 0.0f;
  if (lane < NUM_CLASSES) {
    const float p = (float)hist[lane];
    const float t = (float)hist[NUM_CLASSES + lane];
    const float i = (float)hist[2 * NUM_CLASSES + lane];
    const float u = p + t - i;
    iou = (u > 0.0f) ? (i / (u + 1e-6f)) : 0.0f;
  }
#pragma unroll
  for (int off = 32; off > 0; off >>= 1) iou += __shfl_down(iou, off);
  if (lane == 0) out[0] = iou / (float)NUM_CLASSES;
}

extern "C" void kernel_launch(void* const* d_in, const int* in_sizes, int n_in,
                              void* d_out, int out_size, void* d_ws, size_t ws_size,
                              hipStream_t stream) {
  const float4* pred = (const float4*)d_in[0];
  const int4*   tgt  = (const int4*)d_in[1];
  float*        out  = (float*)d_out;
  unsigned int* hist = (unsigned int*)d_ws;

  // counters must start at zero every call (ws is poisoned once, never re-poisoned)
  hipMemsetAsync(d_ws, 0, 3 * NUM_CLASSES * sizeof(unsigned int), stream);

  iou_hist_kernel<<<2048, 256, 0, stream>>>(pred, tgt, hist);
  iou_finalize_kernel<<<1, 64, 0, stream>>>(hist, out);
}